// Round 7
// baseline (382.846 us; speedup 1.0000x reference)
//
#include <hip/hip_runtime.h>
#include <math.h>

#define NROWS 65536
#define NC    1000
#define NTH   21
#define NBLK1 2048   // k1: 4 waves/block x 8 rows/wave = 32 rows/block
// ws layout (floats): [0,N) unc | [N,2N) conf_signed
// | 2N: 88 bins | 2N+96: ticket (uint)
// | 2N+4096: blk_mn[2048] | +2048: blk_mx[2048] | +2048: blk_s[2048]

__device__ __forceinline__ void row_process(
        float4 r0, float4 r1, float4 r2, float4 r3,
        int lane, int label, int row,
        float* __restrict__ unc_o, float* __restrict__ confs_o,
        float& mn, float& mx, float& ssum)
{
    // ---- wave max, value-only (fmax tree -> v_max3-friendly; then butterfly) ----
    float mA = fmaxf(fmaxf(r0.x, r0.y), fmaxf(r0.z, r0.w));
    float mB = fmaxf(fmaxf(r1.x, r1.y), fmaxf(r1.z, r1.w));
    float mC = fmaxf(fmaxf(r2.x, r2.y), fmaxf(r2.z, r2.w));
    float mD = fmaxf(fmaxf(r3.x, r3.y), fmaxf(r3.z, r3.w));
    float m  = fmaxf(fmaxf(mA, mB), fmaxf(mC, mD));
    #pragma unroll
    for (int off = 1; off < 64; off <<= 1)
        m = fmaxf(m, __shfl_xor(m, off, 64));

    // ---- exp sums: 4 independent partials (short dep chains) ----
#define ACC4(r, se, sx) { \
    float ta = r.x - m, tb = r.y - m, tc = r.z - m, td = r.w - m; \
    float ea = __expf(ta), eb = __expf(tb), ec = __expf(tc), ed = __expf(td); \
    se = (ea + eb) + (ec + ed); \
    sx = fmaf(ea, ta, fmaf(eb, tb, fmaf(ec, tc, ed * td))); }
    float seA, sxA, seB, sxB, seC, sxC, seD, sxD;
    ACC4(r0, seA, sxA) ACC4(r1, seB, sxB) ACC4(r2, seC, sxC) ACC4(r3, seD, sxD)
#undef ACC4
    float se = (seA + seB) + (seC + seD);
    float sx = (sxA + sxB) + (sxC + sxD);
    #pragma unroll
    for (int off = 1; off < 64; off <<= 1) {
        se += __shfl_xor(se, off, 64);
        sx += __shfl_xor(sx, off, 64);
    }

    float Z    = se;
    float logZ = __logf(Z);
    float rZ   = 1.0f / Z;
    float conf = rZ;                        // max prob = exp(m-m)/Z
    float uncv = fmaf(-sx, rZ, logZ);       // entropy = logZ - sx/Z

    int f4 = label >> 2, slot = label & 3, it = f4 >> 6;
    float4 q = (it == 0) ? r0 : (it == 1) ? r1 : (it == 2) ? r2 : r3;
    float cand = (slot == 0) ? q.x : (slot == 1) ? q.y : (slot == 2) ? q.z : q.w;
    float xl = __shfl(cand, f4 & 63, 64);
    float lp = (xl - m) - logZ;

    // acc = (first-occurrence argmax == label). Cheap wave-uniform pre-test:
    // if x[label] != m, label is not a maximum -> acc=false, skip the tie-scan
    // (true for ~99.9% of rows; acc rate ~ 1/1000 with random labels).
    bool accv = false;
    if (xl == m) {
        // min index whose value == m (exact first-occurrence semantics;
        // sentinel -1e30 in r3 tail can never equal m)
        int b0 = lane << 2, b1 = (lane + 64) << 2, b2 = (lane + 128) << 2, b3 = (lane + 192) << 2;
        int mi = 0x7fffffff;
        if (r3.w == m) mi = b3 + 3;  if (r3.z == m) mi = b3 + 2;
        if (r3.y == m) mi = b3 + 1;  if (r3.x == m) mi = b3 + 0;
        if (r2.w == m) mi = b2 + 3;  if (r2.z == m) mi = b2 + 2;
        if (r2.y == m) mi = b2 + 1;  if (r2.x == m) mi = b2 + 0;
        if (r1.w == m) mi = b1 + 3;  if (r1.z == m) mi = b1 + 2;
        if (r1.y == m) mi = b1 + 1;  if (r1.x == m) mi = b1 + 0;
        if (r0.w == m) mi = b0 + 3;  if (r0.z == m) mi = b0 + 2;
        if (r0.y == m) mi = b0 + 1;  if (r0.x == m) mi = b0 + 0;
        #pragma unroll
        for (int off = 1; off < 64; off <<= 1)
            mi = min(mi, __shfl_xor(mi, off, 64));
        accv = (mi == label);
    }

    if (lane == 0) {
        unc_o[row]   = uncv;
        confs_o[row] = accv ? conf : -conf;   // sign carries accuracy bit
    }
    mn = fminf(mn, uncv);
    mx = fmaxf(mx, uncv);
    ssum += lp;
}

#define LOADROW(P, q0, q1, q2, q3) \
    q0 = (P)[lane]; q1 = (P)[lane + 64]; q2 = (P)[lane + 128]; \
    q3 = make_float4(-1e30f, -1e30f, -1e30f, -1e30f); \
    if (lane < 58) q3 = (P)[lane + 192];

__global__ __launch_bounds__(256, 4) void k1_rowstats(
        const float* __restrict__ logits, const int* __restrict__ labels,
        float* __restrict__ unc_o, float* __restrict__ confs_o,
        float* __restrict__ blk_mn, float* __restrict__ blk_mx, float* __restrict__ blk_s,
        float* __restrict__ bins, unsigned* __restrict__ ticket)
{
    // bins + ticket init (block 0 only; k23 consumes after k1 fully retires)
    if (blockIdx.x == 0) {
        if (threadIdx.x < 88) bins[threadIdx.x] = 0.f;
        if (threadIdx.x == 88) *ticket = 0u;
    }

    const int wave = threadIdx.x >> 6;
    const int lane = threadIdx.x & 63;
    const int row0 = (blockIdx.x * 4 + wave) * 8;   // 8 consecutive rows per wave
    const float4* p = (const float4*)(logits + (size_t)row0 * NC);   // row stride = 250 f4

    int lab0 = labels[row0],     lab1 = labels[row0 + 1];
    int lab2 = labels[row0 + 2], lab3 = labels[row0 + 3];
    int lab4 = labels[row0 + 4], lab5 = labels[row0 + 5];
    int lab6 = labels[row0 + 6], lab7 = labels[row0 + 7];

    float mn = 1e30f, mx = -1e30f, ssum = 0.f;
    float4 a0, a1, a2, a3, b0, b1, b2, b3;

    // 2-deep software pipeline: next row's loads in flight under current row's compute
    LOADROW(p,         a0, a1, a2, a3)
    LOADROW(p + 250,   b0, b1, b2, b3)
    row_process(a0, a1, a2, a3, lane, lab0, row0,     unc_o, confs_o, mn, mx, ssum);
    LOADROW(p + 500,   a0, a1, a2, a3)
    row_process(b0, b1, b2, b3, lane, lab1, row0 + 1, unc_o, confs_o, mn, mx, ssum);
    LOADROW(p + 750,   b0, b1, b2, b3)
    row_process(a0, a1, a2, a3, lane, lab2, row0 + 2, unc_o, confs_o, mn, mx, ssum);
    LOADROW(p + 1000,  a0, a1, a2, a3)
    row_process(b0, b1, b2, b3, lane, lab3, row0 + 3, unc_o, confs_o, mn, mx, ssum);
    LOADROW(p + 1250,  b0, b1, b2, b3)
    row_process(a0, a1, a2, a3, lane, lab4, row0 + 4, unc_o, confs_o, mn, mx, ssum);
    LOADROW(p + 1500,  a0, a1, a2, a3)
    row_process(b0, b1, b2, b3, lane, lab5, row0 + 5, unc_o, confs_o, mn, mx, ssum);
    LOADROW(p + 1750,  b0, b1, b2, b3)
    row_process(a0, a1, a2, a3, lane, lab6, row0 + 6, unc_o, confs_o, mn, mx, ssum);
    row_process(b0, b1, b2, b3, lane, lab7, row0 + 7, unc_o, confs_o, mn, mx, ssum);

    // per-block partials (plain stores, no contended atomics)
    __shared__ float s_mn[4], s_mx[4], s_s[4];
    if (lane == 0) { s_mn[wave] = mn; s_mx[wave] = mx; s_s[wave] = ssum; }
    __syncthreads();
    if (threadIdx.x == 0) {
        blk_mn[blockIdx.x] = fminf(fminf(s_mn[0], s_mn[1]), fminf(s_mn[2], s_mn[3]));
        blk_mx[blockIdx.x] = fmaxf(fmaxf(s_mx[0], s_mx[1]), fmaxf(s_mx[2], s_mx[3]));
        blk_s [blockIdx.x] = (s_s[0] + s_s[1]) + (s_s[2] + s_s[3]);
    }
}

// fused reduce + hist + final: every block redundantly reduces the 2048 partials
// (deterministic, identical umin/umax/ce in all blocks); last-done block (ticket)
// reads the completed bins and writes the final scalar. No extra launches.
__global__ __launch_bounds__(256) void k23_hist(
        const float* __restrict__ blk_mn, const float* __restrict__ blk_mx,
        const float* __restrict__ blk_s,
        const float* __restrict__ unc, const float* __restrict__ confs,
        float* __restrict__ bins, unsigned* __restrict__ ticket,
        float* __restrict__ out)
{
    __shared__ float h[88];
    __shared__ float smn[4], smx[4], ss[4];
    for (int i = threadIdx.x; i < 88; i += 256) h[i] = 0.f;

    float mn = 1e30f, mx = -1e30f, s = 0.f;
    for (int i = threadIdx.x; i < NBLK1; i += 256) {
        mn = fminf(mn, blk_mn[i]);
        mx = fmaxf(mx, blk_mx[i]);
        s += blk_s[i];
    }
    #pragma unroll
    for (int off = 1; off < 64; off <<= 1) {
        mn = fminf(mn, __shfl_xor(mn, off, 64));
        mx = fmaxf(mx, __shfl_xor(mx, off, 64));
        s += __shfl_xor(s, off, 64);
    }
    int wave = threadIdx.x >> 6;
    if ((threadIdx.x & 63) == 0) { smn[wave] = mn; smx[wave] = mx; ss[wave] = s; }
    __syncthreads();
    if (threadIdx.x == 0) {
        smn[0] = fminf(fminf(smn[0], smn[1]), fminf(smn[2], smn[3]));
        smx[0] = fmaxf(fmaxf(smx[0], smx[1]), fmaxf(smx[2], smx[3]));
        ss[0]  = (ss[0] + ss[1]) + (ss[2] + ss[3]);
    }
    __syncthreads();
    float umin = smn[0];
    float umax = smx[0];
    float du = umax - umin;

    int i = blockIdx.x * 256 + threadIdx.x;
    float u  = unc[i];
    float cs = confs[i];
    float conf = fabsf(cs);
    bool  acc  = cs > 0.f;
    float tu = tanhf(u);

    // bucket = smallest t with u <= umin + (t*0.05)*du ; 21 => never certain
    int b = NTH;
    #pragma unroll
    for (int t = NTH - 1; t >= 0; --t) {
        float th = umin + ((float)t * 0.05f) * du;
        if (u <= th) b = t;
    }
    float w = acc ? conf : (1.f - conf);
    int base = acc ? 0 : 44;
    atomicAdd(&h[base + b],       w * (1.f - tu));  // -> n_ac / n_ic (certain side)
    atomicAdd(&h[base + 22 + b],  w * tu);          // -> n_au / n_iu (uncertain side)
    __syncthreads();
    for (int i2 = threadIdx.x; i2 < 88; i2 += 256) {
        float v = h[i2];
        if (v != 0.f) atomicAdd(&bins[i2], v);
    }

    // ---- last-done block computes the final scalar (threadfence-reduction pattern) ----
    __threadfence();
    __syncthreads();
    if (threadIdx.x == 0) {
        unsigned t = atomicAdd(ticket, 1u);
        if (t == (unsigned)(gridDim.x - 1)) {
            __threadfence();   // acquire: see all blocks' bins contributions
            float tot_au = 0.f, tot_iu = 0.f;
            for (int bq = 0; bq < 22; ++bq) { tot_au += bins[22 + bq]; tot_iu += bins[66 + bq]; }
            float cac = 0.f, cau = 0.f, cic = 0.f, ciu = 0.f;
            float avu[NTH];
            #pragma unroll
            for (int tt = 0; tt < NTH; ++tt) {
                cac += bins[tt]; cau += bins[22 + tt]; cic += bins[44 + tt]; ciu += bins[66 + tt];
                float nac = cac, nau = tot_au - cau, nic = cic, niu = tot_iu - ciu;
                avu[tt] = (nac + niu) / (nac + nau + nic + niu + 1e-12f);
            }
            float auc = 0.f;
            #pragma unroll
            for (int tt = 0; tt + 1 < NTH; ++tt) auc += 0.5f * (avu[tt + 1] + avu[tt]) * 0.05f;
            float avu_loss = -3.0f * logf(auc + 1e-12f);
            float ce = -ss[0] / (float)NROWS;   // own redundant reduction == global sum
            out[0] = avu_loss + ce;
        }
    }
}

extern "C" void kernel_launch(void* const* d_in, const int* in_sizes, int n_in,
                              void* d_out, int out_size, void* d_ws, size_t ws_size,
                              hipStream_t stream)
{
    const float* logits = (const float*)d_in[0];
    const int*   labels = (const int*)d_in[1];
    float* ws    = (float*)d_ws;
    float* unc   = ws;
    float* confs = ws + NROWS;
    float* bins  = ws + 2 * NROWS;                       // 88 floats
    unsigned* ticket = (unsigned*)(ws + 2 * NROWS + 96);
    float* blk_mn = ws + 2 * NROWS + 4096;
    float* blk_mx = blk_mn + NBLK1;
    float* blk_s  = blk_mx + NBLK1;

    hipLaunchKernelGGL(k1_rowstats, dim3(NBLK1), dim3(256), 0, stream,
                       logits, labels, unc, confs, blk_mn, blk_mx, blk_s, bins, ticket);
    hipLaunchKernelGGL(k23_hist, dim3(NROWS / 256), dim3(256), 0, stream,
                       blk_mn, blk_mx, blk_s, unc, confs, bins, ticket, (float*)d_out);
}

// Round 8
// 356.953 us; speedup vs baseline: 1.0725x; 1.0725x over previous
//
#include <hip/hip_runtime.h>
#include <math.h>

#define NROWS 65536
#define NC    1000
#define NTH   21
#define NBLK1 2048   // k1: 4 waves/block x 8 rows/wave = 32 rows/block
// ws layout (floats): [0,N) unc | [N,2N) conf_signed
// | 2N: 88 bins | 2N+96: ticket (uint)
// | 2N+4096: blk_mn[2048] | +2048: blk_mx[2048] | +2048: blk_s[2048]

// NT loads: logits (262 MB) slightly exceeds L3 (256 MB); cyclic re-read through
// LRU gives ~0% hits + L2/L3 fill thrash. NT streams from HBM without pollution.
// (r5-build with NT: 358.6 us; r6-build plain: 382.8 us — this isolates that delta.)
typedef float f32x4_t __attribute__((ext_vector_type(4)));
__device__ __forceinline__ float4 ntload4(const float4* p) {
    f32x4_t v = __builtin_nontemporal_load((const f32x4_t*)p);
    return make_float4(v.x, v.y, v.z, v.w);
}

__device__ __forceinline__ void row_process(
        float4 r0, float4 r1, float4 r2, float4 r3,
        int lane, int label, int row,
        float* __restrict__ unc_o, float* __restrict__ confs_o,
        float& mn, float& mx, float& ssum)
{
    // ---- wave max, value-only (fmax tree -> v_max3-friendly; then butterfly) ----
    float mA = fmaxf(fmaxf(r0.x, r0.y), fmaxf(r0.z, r0.w));
    float mB = fmaxf(fmaxf(r1.x, r1.y), fmaxf(r1.z, r1.w));
    float mC = fmaxf(fmaxf(r2.x, r2.y), fmaxf(r2.z, r2.w));
    float mD = fmaxf(fmaxf(r3.x, r3.y), fmaxf(r3.z, r3.w));
    float m  = fmaxf(fmaxf(mA, mB), fmaxf(mC, mD));
    #pragma unroll
    for (int off = 1; off < 64; off <<= 1)
        m = fmaxf(m, __shfl_xor(m, off, 64));

    // ---- exp sums: 4 independent partials (short dep chains) ----
#define ACC4(r, se, sx) { \
    float ta = r.x - m, tb = r.y - m, tc = r.z - m, td = r.w - m; \
    float ea = __expf(ta), eb = __expf(tb), ec = __expf(tc), ed = __expf(td); \
    se = (ea + eb) + (ec + ed); \
    sx = fmaf(ea, ta, fmaf(eb, tb, fmaf(ec, tc, ed * td))); }
    float seA, sxA, seB, sxB, seC, sxC, seD, sxD;
    ACC4(r0, seA, sxA) ACC4(r1, seB, sxB) ACC4(r2, seC, sxC) ACC4(r3, seD, sxD)
#undef ACC4
    float se = (seA + seB) + (seC + seD);
    float sx = (sxA + sxB) + (sxC + sxD);
    #pragma unroll
    for (int off = 1; off < 64; off <<= 1) {
        se += __shfl_xor(se, off, 64);
        sx += __shfl_xor(sx, off, 64);
    }

    float Z    = se;
    float logZ = __logf(Z);
    float rZ   = 1.0f / Z;
    float conf = rZ;                        // max prob = exp(m-m)/Z
    float uncv = fmaf(-sx, rZ, logZ);       // entropy = logZ - sx/Z

    int f4 = label >> 2, slot = label & 3, it = f4 >> 6;
    float4 q = (it == 0) ? r0 : (it == 1) ? r1 : (it == 2) ? r2 : r3;
    float cand = (slot == 0) ? q.x : (slot == 1) ? q.y : (slot == 2) ? q.z : q.w;
    float xl = __shfl(cand, f4 & 63, 64);
    float lp = (xl - m) - logZ;

    // acc = (first-occurrence argmax == label). Cheap wave-uniform pre-test:
    // if x[label] != m, label is not a maximum -> acc=false, skip the tie-scan
    // (true for ~99.9% of rows; acc rate ~ 1/1000 with random labels).
    bool accv = false;
    if (xl == m) {
        // min index whose value == m (exact first-occurrence semantics;
        // sentinel -1e30 in r3 tail can never equal m)
        int b0 = lane << 2, b1 = (lane + 64) << 2, b2 = (lane + 128) << 2, b3 = (lane + 192) << 2;
        int mi = 0x7fffffff;
        if (r3.w == m) mi = b3 + 3;  if (r3.z == m) mi = b3 + 2;
        if (r3.y == m) mi = b3 + 1;  if (r3.x == m) mi = b3 + 0;
        if (r2.w == m) mi = b2 + 3;  if (r2.z == m) mi = b2 + 2;
        if (r2.y == m) mi = b2 + 1;  if (r2.x == m) mi = b2 + 0;
        if (r1.w == m) mi = b1 + 3;  if (r1.z == m) mi = b1 + 2;
        if (r1.y == m) mi = b1 + 1;  if (r1.x == m) mi = b1 + 0;
        if (r0.w == m) mi = b0 + 3;  if (r0.z == m) mi = b0 + 2;
        if (r0.y == m) mi = b0 + 1;  if (r0.x == m) mi = b0 + 0;
        #pragma unroll
        for (int off = 1; off < 64; off <<= 1)
            mi = min(mi, __shfl_xor(mi, off, 64));
        accv = (mi == label);
    }

    if (lane == 0) {
        unc_o[row]   = uncv;
        confs_o[row] = accv ? conf : -conf;   // sign carries accuracy bit
    }
    mn = fminf(mn, uncv);
    mx = fmaxf(mx, uncv);
    ssum += lp;
}

#define LOADROW(P, q0, q1, q2, q3) \
    q0 = ntload4((P) + lane); q1 = ntload4((P) + lane + 64); q2 = ntload4((P) + lane + 128); \
    q3 = make_float4(-1e30f, -1e30f, -1e30f, -1e30f); \
    if (lane < 58) q3 = ntload4((P) + lane + 192);

__global__ __launch_bounds__(256, 4) void k1_rowstats(
        const float* __restrict__ logits, const int* __restrict__ labels,
        float* __restrict__ unc_o, float* __restrict__ confs_o,
        float* __restrict__ blk_mn, float* __restrict__ blk_mx, float* __restrict__ blk_s,
        float* __restrict__ bins, unsigned* __restrict__ ticket)
{
    // bins + ticket init (block 0 only; k23 consumes after k1 fully retires)
    if (blockIdx.x == 0) {
        if (threadIdx.x < 88) bins[threadIdx.x] = 0.f;
        if (threadIdx.x == 88) *ticket = 0u;
    }

    const int wave = threadIdx.x >> 6;
    const int lane = threadIdx.x & 63;
    const int row0 = (blockIdx.x * 4 + wave) * 8;   // 8 consecutive rows per wave
    const float4* p = (const float4*)(logits + (size_t)row0 * NC);   // row stride = 250 f4

    int lab0 = labels[row0],     lab1 = labels[row0 + 1];
    int lab2 = labels[row0 + 2], lab3 = labels[row0 + 3];
    int lab4 = labels[row0 + 4], lab5 = labels[row0 + 5];
    int lab6 = labels[row0 + 6], lab7 = labels[row0 + 7];

    float mn = 1e30f, mx = -1e30f, ssum = 0.f;
    float4 a0, a1, a2, a3, b0, b1, b2, b3;

    // 2-deep software pipeline: next row's loads in flight under current row's compute
    LOADROW(p,         a0, a1, a2, a3)
    LOADROW(p + 250,   b0, b1, b2, b3)
    row_process(a0, a1, a2, a3, lane, lab0, row0,     unc_o, confs_o, mn, mx, ssum);
    LOADROW(p + 500,   a0, a1, a2, a3)
    row_process(b0, b1, b2, b3, lane, lab1, row0 + 1, unc_o, confs_o, mn, mx, ssum);
    LOADROW(p + 750,   b0, b1, b2, b3)
    row_process(a0, a1, a2, a3, lane, lab2, row0 + 2, unc_o, confs_o, mn, mx, ssum);
    LOADROW(p + 1000,  a0, a1, a2, a3)
    row_process(b0, b1, b2, b3, lane, lab3, row0 + 3, unc_o, confs_o, mn, mx, ssum);
    LOADROW(p + 1250,  b0, b1, b2, b3)
    row_process(a0, a1, a2, a3, lane, lab4, row0 + 4, unc_o, confs_o, mn, mx, ssum);
    LOADROW(p + 1500,  a0, a1, a2, a3)
    row_process(b0, b1, b2, b3, lane, lab5, row0 + 5, unc_o, confs_o, mn, mx, ssum);
    LOADROW(p + 1750,  b0, b1, b2, b3)
    row_process(a0, a1, a2, a3, lane, lab6, row0 + 6, unc_o, confs_o, mn, mx, ssum);
    row_process(b0, b1, b2, b3, lane, lab7, row0 + 7, unc_o, confs_o, mn, mx, ssum);

    // per-block partials (plain stores, no contended atomics)
    __shared__ float s_mn[4], s_mx[4], s_s[4];
    if (lane == 0) { s_mn[wave] = mn; s_mx[wave] = mx; s_s[wave] = ssum; }
    __syncthreads();
    if (threadIdx.x == 0) {
        blk_mn[blockIdx.x] = fminf(fminf(s_mn[0], s_mn[1]), fminf(s_mn[2], s_mn[3]));
        blk_mx[blockIdx.x] = fmaxf(fmaxf(s_mx[0], s_mx[1]), fmaxf(s_mx[2], s_mx[3]));
        blk_s [blockIdx.x] = (s_s[0] + s_s[1]) + (s_s[2] + s_s[3]);
    }
}

// fused reduce + hist + final: every block redundantly reduces the 2048 partials
// (deterministic, identical umin/umax/ce in all blocks); last-done block (ticket)
// reads the completed bins and writes the final scalar. No extra launches.
__global__ __launch_bounds__(256) void k23_hist(
        const float* __restrict__ blk_mn, const float* __restrict__ blk_mx,
        const float* __restrict__ blk_s,
        const float* __restrict__ unc, const float* __restrict__ confs,
        float* __restrict__ bins, unsigned* __restrict__ ticket,
        float* __restrict__ out)
{
    __shared__ float h[88];
    __shared__ float smn[4], smx[4], ss[4];
    for (int i = threadIdx.x; i < 88; i += 256) h[i] = 0.f;

    float mn = 1e30f, mx = -1e30f, s = 0.f;
    for (int i = threadIdx.x; i < NBLK1; i += 256) {
        mn = fminf(mn, blk_mn[i]);
        mx = fmaxf(mx, blk_mx[i]);
        s += blk_s[i];
    }
    #pragma unroll
    for (int off = 1; off < 64; off <<= 1) {
        mn = fminf(mn, __shfl_xor(mn, off, 64));
        mx = fmaxf(mx, __shfl_xor(mx, off, 64));
        s += __shfl_xor(s, off, 64);
    }
    int wave = threadIdx.x >> 6;
    if ((threadIdx.x & 63) == 0) { smn[wave] = mn; smx[wave] = mx; ss[wave] = s; }
    __syncthreads();
    if (threadIdx.x == 0) {
        smn[0] = fminf(fminf(smn[0], smn[1]), fminf(smn[2], smn[3]));
        smx[0] = fmaxf(fmaxf(smx[0], smx[1]), fmaxf(smx[2], smx[3]));
        ss[0]  = (ss[0] + ss[1]) + (ss[2] + ss[3]);
    }
    __syncthreads();
    float umin = smn[0];
    float umax = smx[0];
    float du = umax - umin;

    int i = blockIdx.x * 256 + threadIdx.x;
    float u  = unc[i];
    float cs = confs[i];
    float conf = fabsf(cs);
    bool  acc  = cs > 0.f;
    float tu = tanhf(u);

    // bucket = smallest t with u <= umin + (t*0.05)*du ; 21 => never certain
    int b = NTH;
    #pragma unroll
    for (int t = NTH - 1; t >= 0; --t) {
        float th = umin + ((float)t * 0.05f) * du;
        if (u <= th) b = t;
    }
    float w = acc ? conf : (1.f - conf);
    int base = acc ? 0 : 44;
    atomicAdd(&h[base + b],       w * (1.f - tu));  // -> n_ac / n_ic (certain side)
    atomicAdd(&h[base + 22 + b],  w * tu);          // -> n_au / n_iu (uncertain side)
    __syncthreads();
    for (int i2 = threadIdx.x; i2 < 88; i2 += 256) {
        float v = h[i2];
        if (v != 0.f) atomicAdd(&bins[i2], v);
    }

    // ---- last-done block computes the final scalar (threadfence-reduction pattern) ----
    __threadfence();
    __syncthreads();
    if (threadIdx.x == 0) {
        unsigned t = atomicAdd(ticket, 1u);
        if (t == (unsigned)(gridDim.x - 1)) {
            __threadfence();   // acquire: see all blocks' bins contributions
            float tot_au = 0.f, tot_iu = 0.f;
            for (int bq = 0; bq < 22; ++bq) { tot_au += bins[22 + bq]; tot_iu += bins[66 + bq]; }
            float cac = 0.f, cau = 0.f, cic = 0.f, ciu = 0.f;
            float avu[NTH];
            #pragma unroll
            for (int tt = 0; tt < NTH; ++tt) {
                cac += bins[tt]; cau += bins[22 + tt]; cic += bins[44 + tt]; ciu += bins[66 + tt];
                float nac = cac, nau = tot_au - cau, nic = cic, niu = tot_iu - ciu;
                avu[tt] = (nac + niu) / (nac + nau + nic + niu + 1e-12f);
            }
            float auc = 0.f;
            #pragma unroll
            for (int tt = 0; tt + 1 < NTH; ++tt) auc += 0.5f * (avu[tt + 1] + avu[tt]) * 0.05f;
            float avu_loss = -3.0f * logf(auc + 1e-12f);
            float ce = -ss[0] / (float)NROWS;   // own redundant reduction == global sum
            out[0] = avu_loss + ce;
        }
    }
}

extern "C" void kernel_launch(void* const* d_in, const int* in_sizes, int n_in,
                              void* d_out, int out_size, void* d_ws, size_t ws_size,
                              hipStream_t stream)
{
    const float* logits = (const float*)d_in[0];
    const int*   labels = (const int*)d_in[1];
    float* ws    = (float*)d_ws;
    float* unc   = ws;
    float* confs = ws + NROWS;
    float* bins  = ws + 2 * NROWS;                       // 88 floats
    unsigned* ticket = (unsigned*)(ws + 2 * NROWS + 96);
    float* blk_mn = ws + 2 * NROWS + 4096;
    float* blk_mx = blk_mn + NBLK1;
    float* blk_s  = blk_mx + NBLK1;

    hipLaunchKernelGGL(k1_rowstats, dim3(NBLK1), dim3(256), 0, stream,
                       logits, labels, unc, confs, blk_mn, blk_mx, blk_s, bins, ticket);
    hipLaunchKernelGGL(k23_hist, dim3(NROWS / 256), dim3(256), 0, stream,
                       blk_mn, blk_mx, blk_s, unc, confs, bins, ticket, (float*)d_out);
}